// Round 4
// baseline (184.599 us; speedup 1.0000x reference)
//
#include <hip/hip_runtime.h>
#include <hip/hip_fp16.h>

typedef unsigned long long u64;
typedef unsigned int uint32;
typedef short short8 __attribute__((ext_vector_type(8)));
typedef float f32x4 __attribute__((ext_vector_type(4)));
typedef _Float16 h2 __attribute__((ext_vector_type(2)));

#define B_N 8192
#define L_N 1024
#define M_N 128
#define C_N 16         // chunks over L
#define CH_N 64        // steps per chunk
#define HALF_N 512

// ws layout (bytes) — proven 35.3MB footprint
#define OFF_W16  0           // w16[i][m] fp16: 256KB
#define OFF_R16  0x40000     // r16[i][m] fp16 (stores r-1): 256KB
#define OFF_BITS 0x80000     // bits[b][16] u64: 1MB
#define OFF_LR   0x180000    // lrT[m][t] bf16: 256KB
#define OFF_RQ   0x1C0000    // Rq[c][b][m] fp16: 32MB
#define OFF_T    0x21C0000   // T[b] int32: 32KB

#define PACK_BLK 2048
#define PACK_IT  16          // 2048*256*16 = B*L
#define EPS_BLK  32
#define ZERO_BLK 32

__device__ __forceinline__ unsigned short f32_bf16(float f) {
    union { float f; unsigned u; } x; x.f = f;
    unsigned u = x.u + 0x7FFFu + ((x.u >> 16) & 1u);   // RNE
    return (unsigned short)(u >> 16);
}

__device__ __forceinline__ float fdot2(h2 a, h2 b, float c) {
#if __has_builtin(__builtin_amdgcn_fdot2)
    return __builtin_amdgcn_fdot2(a, b, c, false);
#else
    return (float)a[0] * (float)b[0] + (float)a[1] * (float)b[1] + c;
#endif
}

__device__ __forceinline__ uint32 fas_u(float f) { union { float f; uint32 u; } x; x.f = f; return x.u; }
__device__ __forceinline__ float uas_f(uint32 u) { union { uint32 u; float f; } x; x.u = u; return x.f; }

// x + dpp(y). CTRL: 0xB1 = quad_perm[1,0,3,2] (xor1), 0x4E = quad_perm[2,3,0,1]
// (xor2), 0x104 = row_shl:4 (dest[i]=src[i+4], HW-proven r3), 0x108 = row_shl:8.
// bound_ctrl=1 zero-fills lanes shifted past the 16-lane row; we only consume s<4.
template<int CTRL>
__device__ __forceinline__ float dpp_add(float x, float y) {
    union { float f; int i; } a, r;
    a.f = y;
    r.i = __builtin_amdgcn_update_dpp(0, a.i, CTRL, 0xF, 0xF, true);
    return x + r.f;
}

union HU { uint32 u; __half2 hh; h2 v2; };

// ---- K0: fused prep: spin-pack | eps tables (fp16) | zero out -----------
__global__ __launch_bounds__(256) void k_prep(const int* __restrict__ inp,
        const float* __restrict__ eps, u64* __restrict__ bits,
        _Float16* __restrict__ w16, _Float16* __restrict__ r16,
        unsigned short* __restrict__ lrT, float* __restrict__ out) {
    int bid = blockIdx.x;
    if (bid < PACK_BLK) {
        int g = bid * 256 + threadIdx.x;
        const int stride = PACK_BLK * 256;
        #pragma unroll 4
        for (int it = 0; it < PACK_IT; ++it) {
            int v = inp[g];
            u64 m = __ballot(v != 0);
            if ((threadIdx.x & 63) == 0) bits[g >> 6] = m;
            g += stride;
        }
        return;
    }
    bid -= PACK_BLK;
    if (bid < EPS_BLK) {
        int wid = threadIdx.x >> 6, lane = threadIdx.x & 63;
        int m = bid * 4 + wid;
        const float* e0 = eps + (size_t)m * L_N + lane * 16;
        const float* e1 = eps + (size_t)(M_N + m) * L_N + lane * 16;
        float a[16], b[16];
        #pragma unroll
        for (int j = 0; j < 16; j += 4) {
            *(float4*)&a[j] = *(const float4*)&e0[j];
            *(float4*)&b[j] = *(const float4*)&e1[j];
        }
        float local = 1.f;
        #pragma unroll
        for (int j = 0; j < 16; ++j) local *= a[j];
        float sc = local;
        #pragma unroll
        for (int d = 1; d < 64; d <<= 1) {
            float up = __shfl_up(sc, d);
            if (lane >= d) sc *= up;
        }
        float prev = __shfl_up(sc, 1);
        float E = (lane == 0) ? 1.f : prev;
        int i0 = lane * 16;
        #pragma unroll
        for (int j = 0; j < 16; ++j) {
            float rat = b[j] / a[j];
            w16[(size_t)(i0 + j) * M_N + m] = (_Float16)(E * (a[j] - b[j]));
            r16[(size_t)(i0 + j) * M_N + m] = (_Float16)(rat - 1.f);   // r-1 for pk_fma
            lrT[(size_t)m * L_N + i0 + j] = f32_bf16(__log2f(rat));
            E *= a[j];
        }
        return;
    }
    bid -= EPS_BLK;
    if (bid < ZERO_BLK) {
        out[bid * 256 + threadIdx.x] = 0.f;
    }
}

// ---- K2: MFMA chunk log-sums + f32 cumsum + exp2 -> fp16 excl prefix ----
// blocks [0,1024): prefix; blocks [1024,1056): per-b saturation step T.
__global__ __launch_bounds__(256) void k_slog2(const u64* __restrict__ bits,
        const unsigned short* __restrict__ lrT, _Float16* __restrict__ Rq,
        int* __restrict__ T) {
    if (blockIdx.x >= 1024) {
        int b = (blockIdx.x - 1024) * 256 + threadIdx.x;
        const u64* brow = bits + (size_t)b * 16;
        int n1 = 0, n0 = 0, Tv = 1024;
        for (int wd = 0; wd < 16; ++wd) {
            u64 x = brow[wd];
            int pc = __popcll(x);
            if (n1 + pc < HALF_N && n0 + (64 - pc) < HALF_N) {
                n1 += pc; n0 += 64 - pc;
                continue;
            }
            int found = 0;
            for (int k = 0; k < 64; ++k) {
                if (n1 >= HALF_N || n0 >= HALF_N) { Tv = wd * 64 + k; found = 1; break; }
                int sb = (int)((x >> k) & 1);
                n1 += sb; n0 += 1 - sb;
            }
            if (!found) Tv = (wd + 1) * 64;
            break;
        }
        T[b] = Tv;
        return;
    }
    int btile = blockIdx.x >> 1;
    int half = blockIdx.x & 1;
    int wid = threadIdx.x >> 6, lane = threadIdx.x & 63;
    int col = lane & 15, quad = lane >> 4;
    int m = (half * 4 + wid) * 16 + col;
    int b_row = btile * 16 + col;
    const u64* brow = bits + (size_t)b_row * 16;
    const unsigned short* lrow = lrT + (size_t)m * L_N;

    f32x4 cum = (f32x4){0.f, 0.f, 0.f, 0.f};

    for (int c = 0; c < C_N; ++c) {
        #pragma unroll
        for (int reg = 0; reg < 4; ++reg) {
            int b = btile * 16 + quad * 4 + reg;
            Rq[((size_t)c * B_N + b) * M_N + m] = (_Float16)exp2f(cum[reg]);
        }
        u64 wv = brow[c];
        short8 a0, a1;
        #pragma unroll
        for (int j = 0; j < 8; ++j) {
            a0[j] = (short)((((wv >> (quad * 8 + j)) & 1) != 0) ? 0x3F80 : 0);
            a1[j] = (short)((((wv >> (32 + quad * 8 + j)) & 1) != 0) ? 0x3F80 : 0);
        }
        const unsigned short* bp = lrow + c * 64 + quad * 8;
        union { uint4 u; short8 s; } bf0, bf1;
        bf0.u = *(const uint4*)bp;
        bf1.u = *(const uint4*)(bp + 32);
        cum = __builtin_amdgcn_mfma_f32_16x16x32_bf16(a0, bf0.s, cum, 0, 0, 0);
        cum = __builtin_amdgcn_mfma_f32_16x16x32_bf16(a1, bf1.s, cum, 0, 0, 0);
    }
}

// ------- K3: main loop — m8/nb4, k-permuted b's, select-free DPP reduce --
// 16 lanes (one DPP row) handle 4 b's x 128 m's; thread s owns m-slice
// s*8..s*8+7 and R2[k] = running product for b0 + ((s&3)^k). The k-permute
// makes the butterfly reduce select-free: partner lane s^1's d[1] is OUR b.
__global__ __launch_bounds__(256, 4) void k_main(const u64* __restrict__ bits,
        const _Float16* __restrict__ w16, const _Float16* __restrict__ r16,
        const _Float16* __restrict__ Rq, const int* __restrict__ T,
        float* __restrict__ out) {
    __shared__ _Float16 wbuf[CH_N * M_N];   // 16KB
    __shared__ _Float16 rbuf[CH_N * M_N];   // 16KB
    int c = blockIdx.x & (C_N - 1);
    int bblk = blockIdx.x >> 4;
    int lane = threadIdx.x & 63, wid = threadIdx.x >> 6;
    int s = lane & 15, row = lane >> 4;
    int q = s & 3;
    int b0 = bblk * 64 + wid * 16 + row * 4;

    // stage full chunk (16KB per table, coalesced uint4)
    {
        const uint4* sw = (const uint4*)(w16 + (size_t)c * CH_N * M_N);
        const uint4* sr = (const uint4*)(r16 + (size_t)c * CH_N * M_N);
        uint4* dw = (uint4*)wbuf; uint4* dr = (uint4*)rbuf;
        #pragma unroll
        for (int t = 0; t < 4; ++t) {
            dw[threadIdx.x + t * 256] = sw[threadIdx.x + t * 256];
            dr[threadIdx.x + t * 256] = sr[threadIdx.x + t * 256];
        }
    }

    // prefix load: R2[k][j] = packed pair for b0+(q^k), m = s*8+2j
    HU R2[4][4];
    u64 wb[4];
    #pragma unroll
    for (int k = 0; k < 4; ++k) {
        int b = b0 + (q ^ k);
        union { uint4 v; uint32 w[4]; } P;
        P.v = *(const uint4*)(Rq + ((size_t)c * B_N + b) * M_N + s * 8);
        #pragma unroll
        for (int j = 0; j < 4; ++j) R2[k][j].u = P.w[j];
        wb[k] = bits[(size_t)b * 16 + c];
    }
    int Tb = T[b0 + q];

    __syncthreads();

    const float LOG2E2 = 2.885390082f; // 2*log2(e)
    const float NHL2 = -0.3465735903f; // -0.5*ln2
    float sum = 0.f;
    #pragma unroll
    for (int h = 0; h < 2; ++h) {
        uint32 wh[4];
        #pragma unroll
        for (int k = 0; k < 4; ++k) wh[k] = (uint32)(wb[k] >> (h * 32));
        uint32 ows = ~wh[0];                   // own b's word; bit==0 -> flip sign
        int rel = Tb - (c * CH_N + h * 32);
        uint32 vmask = (rel <= 0) ? 0u : ((rel >= 32) ? 0xFFFFFFFFu : ((1u << rel) - 1u));

        for (int tt = 0; tt < 32; ++tt) {
            int base = (h * 32 + tt) * M_N + s * 8;
            union { uint4 q4; uint32 w[4]; h2 v2[4]; } W, Rm;
            W.q4 = *(const uint4*)&wbuf[base];
            Rm.q4 = *(const uint4*)&rbuf[base];

            float d[4];
            #pragma unroll
            for (int k = 0; k < 4; ++k) {
                float acc = 0.f;
                #pragma unroll
                for (int j = 0; j < 4; ++j) acc = fdot2(R2[k][j].v2, W.v2[j], acc);
                d[k] = acc;
            }
            // select-free butterfly: each stage's partner holds OUR b's partial
            float xa = dpp_add<0xB1>(d[0], d[1]);   // + lane s^1 (its d[1] = our b)
            float xb = dpp_add<0xB1>(d[2], d[3]);   // partial for b^2
            float uD = dpp_add<0x4E>(xa, xb);       // + lane s^2 (its xb = our b)
            uD = dpp_add<0x108>(uD, uD);            // + lane s+8 (row_shl:8)
            uD = dpp_add<0x104>(uD, uD);            // + lane s+4 (row_shl:4)

            // softplus: -0.5*ln2 * log2(1 + 2^(2*log2e*y)), y = +-D by sign-xor
            uint32 sgn = (ows << (31 - tt)) & 0x80000000u;
            float y = uas_f(fas_u(uD) ^ sgn);
            float contr = NHL2 * __log2f(1.f + exp2f(LOG2E2 * y));
            int vm = (int)(vmask << (31 - tt)) >> 31;
            sum += uas_f(fas_u(contr) & (uint32)vm);

            // update: R2 *= (1 + (r-1)&mask)  (AND-mask + packed fma)
            #pragma unroll
            for (int k = 0; k < 4; ++k) {
                uint32 msk = (uint32)((int)(wh[k] << (31 - tt)) >> 31);
                #pragma unroll
                for (int j = 0; j < 4; ++j) {
                    HU sel; sel.u = Rm.w[j] & msk;
                    R2[k][j].v2 += sel.v2 * R2[k][j].v2;
                }
            }
        }
    }
    if (s < 4) atomicAdd(&out[b0 + s], sum);
}

extern "C" void kernel_launch(void* const* d_in, const int* in_sizes, int n_in,
                              void* d_out, int out_size, void* d_ws, size_t ws_size,
                              hipStream_t stream) {
    const int*   inputs  = (const int*)d_in[0];     // (B, L) int32
    const float* epsilon = (const float*)d_in[1];   // (D, M, L) f32
    float* out = (float*)d_out;                     // (B,) f32

    char* ws = (char*)d_ws;
    _Float16* w16 = (_Float16*)(ws + OFF_W16);
    _Float16* r16 = (_Float16*)(ws + OFF_R16);
    u64*   bits   = (u64*)  (ws + OFF_BITS);
    unsigned short* lrT = (unsigned short*)(ws + OFF_LR);
    _Float16* Rq  = (_Float16*)(ws + OFF_RQ);
    int*   T      = (int*)  (ws + OFF_T);

    k_prep<<<PACK_BLK + EPS_BLK + ZERO_BLK, 256, 0, stream>>>(
        inputs, epsilon, bits, w16, r16, lrT, out);
    k_slog2<<<1024 + 32, 256, 0, stream>>>(bits, lrT, Rq, T);
    k_main<<<(B_N / 64) * C_N, 256, 0, stream>>>(bits, w16, r16, Rq, T, out);
}

// Round 5
// 171.285 us; speedup vs baseline: 1.0777x; 1.0777x over previous
//
#include <hip/hip_runtime.h>
#include <hip/hip_fp16.h>

typedef unsigned long long u64;
typedef unsigned int uint32;
typedef short short8 __attribute__((ext_vector_type(8)));
typedef float f32x4 __attribute__((ext_vector_type(4)));
typedef _Float16 h2 __attribute__((ext_vector_type(2)));

#define B_N 8192
#define L_N 1024
#define M_N 128
#define C_N 16         // chunks over L
#define CH_N 64        // steps per chunk
#define HALF_N 512

// ws layout (bytes) — proven 35.3MB footprint
#define OFF_W16  0           // w16[i][m] fp16: 256KB
#define OFF_R16  0x40000     // r16[i][m] fp16 (stores r-1): 256KB
#define OFF_BITS 0x80000     // bits[b][16] u64: 1MB
#define OFF_LR   0x180000    // lrT[m][t] bf16: 256KB
#define OFF_RQ   0x1C0000    // Rq[c][b][m] fp16: 32MB
#define OFF_T    0x21C0000   // T[b] int32: 32KB

#define PACK_BLK 2048
#define PACK_IT  16          // 2048*256*16 = B*L
#define EPS_BLK  32
#define ZERO_BLK 32

__device__ __forceinline__ unsigned short f32_bf16(float f) {
    union { float f; unsigned u; } x; x.f = f;
    unsigned u = x.u + 0x7FFFu + ((x.u >> 16) & 1u);   // RNE
    return (unsigned short)(u >> 16);
}

__device__ __forceinline__ float fdot2(h2 a, h2 b, float c) {
#if __has_builtin(__builtin_amdgcn_fdot2)
    return __builtin_amdgcn_fdot2(a, b, c, false);
#else
    return (float)a[0] * (float)b[0] + (float)a[1] * (float)b[1] + c;
#endif
}

__device__ __forceinline__ uint32 fas_u(float f) { union { float f; uint32 u; } x; x.f = f; return x.u; }
__device__ __forceinline__ float uas_f(uint32 u) { union { uint32 u; float f; } x; x.u = u; return x.f; }

// single-instr raw transcendentals (v_exp_f32 / v_log_f32); range proven
// finite by the passing R0 run of the same formula.
__device__ __forceinline__ float exp2_n(float x) {
#if __has_builtin(__builtin_amdgcn_exp2f)
    return __builtin_amdgcn_exp2f(x);
#else
    return exp2f(x);
#endif
}
__device__ __forceinline__ float log2_n(float x) {
#if __has_builtin(__builtin_amdgcn_logf)
    return __builtin_amdgcn_logf(x);
#else
    return __log2f(x);
#endif
}
// sign-extended single-bit extract: 0 or 0xFFFFFFFF (v_bfe_i32, 1 instr)
__device__ __forceinline__ uint32 bfe1(uint32 v, int off) {
#if __has_builtin(__builtin_amdgcn_sbfe)
    return (uint32)__builtin_amdgcn_sbfe((int)v, off, 1);
#else
    return (uint32)((int)(v << (31 - off)) >> 31);
#endif
}

// x + dpp(y). CTRL: 0xB1 = quad_perm[1,0,3,2] (xor1), 0x4E = quad_perm[2,3,0,1]
// (xor2), 0x104 = row_shl:4 (dest[i]=src[i+4]) — all HW-proven in r3/r4.
template<int CTRL>
__device__ __forceinline__ float dpp_add(float x, float y) {
    union { float f; int i; } a, r;
    a.f = y;
    r.i = __builtin_amdgcn_update_dpp(0, a.i, CTRL, 0xF, 0xF, true);
    return x + r.f;
}

union HU { uint32 u; __half2 hh; h2 v2; };

// ---- K0: fused prep: spin-pack | eps tables (fp16) | zero out -----------
__global__ __launch_bounds__(256) void k_prep(const int* __restrict__ inp,
        const float* __restrict__ eps, u64* __restrict__ bits,
        _Float16* __restrict__ w16, _Float16* __restrict__ r16,
        unsigned short* __restrict__ lrT, float* __restrict__ out) {
    int bid = blockIdx.x;
    if (bid < PACK_BLK) {
        int g = bid * 256 + threadIdx.x;
        const int stride = PACK_BLK * 256;
        #pragma unroll 4
        for (int it = 0; it < PACK_IT; ++it) {
            int v = inp[g];
            u64 m = __ballot(v != 0);
            if ((threadIdx.x & 63) == 0) bits[g >> 6] = m;
            g += stride;
        }
        return;
    }
    bid -= PACK_BLK;
    if (bid < EPS_BLK) {
        int wid = threadIdx.x >> 6, lane = threadIdx.x & 63;
        int m = bid * 4 + wid;
        const float* e0 = eps + (size_t)m * L_N + lane * 16;
        const float* e1 = eps + (size_t)(M_N + m) * L_N + lane * 16;
        float a[16], b[16];
        #pragma unroll
        for (int j = 0; j < 16; j += 4) {
            *(float4*)&a[j] = *(const float4*)&e0[j];
            *(float4*)&b[j] = *(const float4*)&e1[j];
        }
        float local = 1.f;
        #pragma unroll
        for (int j = 0; j < 16; ++j) local *= a[j];
        float sc = local;
        #pragma unroll
        for (int d = 1; d < 64; d <<= 1) {
            float up = __shfl_up(sc, d);
            if (lane >= d) sc *= up;
        }
        float prev = __shfl_up(sc, 1);
        float E = (lane == 0) ? 1.f : prev;
        int i0 = lane * 16;
        #pragma unroll
        for (int j = 0; j < 16; ++j) {
            float rat = b[j] / a[j];
            w16[(size_t)(i0 + j) * M_N + m] = (_Float16)(E * (a[j] - b[j]));
            r16[(size_t)(i0 + j) * M_N + m] = (_Float16)(rat - 1.f);   // r-1 for pk_fma
            lrT[(size_t)m * L_N + i0 + j] = f32_bf16(__log2f(rat));
            E *= a[j];
        }
        return;
    }
    bid -= EPS_BLK;
    if (bid < ZERO_BLK) {
        out[bid * 256 + threadIdx.x] = 0.f;
    }
}

// ---- K2: MFMA chunk log-sums + f32 cumsum + exp2 -> fp16 excl prefix ----
// blocks [0,1024): prefix; blocks [1024,1056): per-b saturation step T.
__global__ __launch_bounds__(256) void k_slog2(const u64* __restrict__ bits,
        const unsigned short* __restrict__ lrT, _Float16* __restrict__ Rq,
        int* __restrict__ T) {
    if (blockIdx.x >= 1024) {
        int b = (blockIdx.x - 1024) * 256 + threadIdx.x;
        const u64* brow = bits + (size_t)b * 16;
        int n1 = 0, n0 = 0, Tv = 1024;
        for (int wd = 0; wd < 16; ++wd) {
            u64 x = brow[wd];
            int pc = __popcll(x);
            if (n1 + pc < HALF_N && n0 + (64 - pc) < HALF_N) {
                n1 += pc; n0 += 64 - pc;
                continue;
            }
            int found = 0;
            for (int k = 0; k < 64; ++k) {
                if (n1 >= HALF_N || n0 >= HALF_N) { Tv = wd * 64 + k; found = 1; break; }
                int sb = (int)((x >> k) & 1);
                n1 += sb; n0 += 1 - sb;
            }
            if (!found) Tv = (wd + 1) * 64;
            break;
        }
        T[b] = Tv;
        return;
    }
    int btile = blockIdx.x >> 1;
    int half = blockIdx.x & 1;
    int wid = threadIdx.x >> 6, lane = threadIdx.x & 63;
    int col = lane & 15, quad = lane >> 4;
    int m = (half * 4 + wid) * 16 + col;
    int b_row = btile * 16 + col;
    const u64* brow = bits + (size_t)b_row * 16;
    const unsigned short* lrow = lrT + (size_t)m * L_N;

    f32x4 cum = (f32x4){0.f, 0.f, 0.f, 0.f};

    for (int c = 0; c < C_N; ++c) {
        #pragma unroll
        for (int reg = 0; reg < 4; ++reg) {
            int b = btile * 16 + quad * 4 + reg;
            Rq[((size_t)c * B_N + b) * M_N + m] = (_Float16)exp2_n(cum[reg]);
        }
        u64 wv = brow[c];
        short8 a0, a1;
        #pragma unroll
        for (int j = 0; j < 8; ++j) {
            a0[j] = (short)((((wv >> (quad * 8 + j)) & 1) != 0) ? 0x3F80 : 0);
            a1[j] = (short)((((wv >> (32 + quad * 8 + j)) & 1) != 0) ? 0x3F80 : 0);
        }
        const unsigned short* bp = lrow + c * 64 + quad * 8;
        union { uint4 u; short8 s; } bf0, bf1;
        bf0.u = *(const uint4*)bp;
        bf1.u = *(const uint4*)(bp + 32);
        cum = __builtin_amdgcn_mfma_f32_16x16x32_bf16(a0, bf0.s, cum, 0, 0, 0);
        cum = __builtin_amdgcn_mfma_f32_16x16x32_bf16(a1, bf1.s, cum, 0, 0, 0);
    }
}

// ------- K3: main loop — R0 geometry (G=8, 4 b, grid 1024) + k-permuted
// select-free DPP reduce + bfe masks + native exp2/log2.
// 8 lanes (s=0..7) handle 4 b's x 128 m's; lane s owns m-slice s*16..s*16+15;
// R2[k] = running product for b0 + ((s&3)^k). k-permute makes the butterfly
// select-free: each stage's DPP partner holds OUR b's partial.
__global__ __launch_bounds__(256, 2) void k_main(const u64* __restrict__ bits,
        const _Float16* __restrict__ w16, const _Float16* __restrict__ r16,
        const _Float16* __restrict__ Rq, const int* __restrict__ T,
        float* __restrict__ out) {
    __shared__ _Float16 wbuf[CH_N * M_N];   // 16KB
    __shared__ _Float16 rbuf[CH_N * M_N];   // 16KB
    int c = blockIdx.x & (C_N - 1);
    int bblk = blockIdx.x >> 4;
    int lane = threadIdx.x & 63, wid = threadIdx.x >> 6;
    int s = lane & 7, grp = lane >> 3;
    int q = s & 3;
    int b0 = bblk * 128 + wid * 32 + grp * 4;

    // stage full chunk (16KB per table, coalesced uint4)
    {
        const uint4* sw = (const uint4*)(w16 + (size_t)c * CH_N * M_N);
        const uint4* sr = (const uint4*)(r16 + (size_t)c * CH_N * M_N);
        uint4* dw = (uint4*)wbuf; uint4* dr = (uint4*)rbuf;
        #pragma unroll
        for (int t = 0; t < 4; ++t) {
            dw[threadIdx.x + t * 256] = sw[threadIdx.x + t * 256];
            dr[threadIdx.x + t * 256] = sr[threadIdx.x + t * 256];
        }
    }

    // prefix load: R2[k][j] = packed pair for b0+(q^k), m = s*16+2j
    HU R2[4][8];
    u64 wb[4];
    #pragma unroll
    for (int k = 0; k < 4; ++k) {
        int b = b0 + (q ^ k);
        union { uint4 v[2]; uint32 w[8]; } P;
        const uint4* src = (const uint4*)(Rq + ((size_t)c * B_N + b) * M_N + s * 16);
        P.v[0] = src[0]; P.v[1] = src[1];
        #pragma unroll
        for (int j = 0; j < 8; ++j) R2[k][j].u = P.w[j];
        wb[k] = bits[(size_t)b * 16 + c];
    }
    int Tb = T[b0 + q];

    __syncthreads();

    const float LOG2E2 = 2.885390082f; // 2*log2(e)
    const float NHL2 = -0.3465735903f; // -0.5*ln2
    float sum = 0.f;
    #pragma unroll
    for (int h = 0; h < 2; ++h) {
        uint32 wh[4];
        #pragma unroll
        for (int k = 0; k < 4; ++k) wh[k] = (uint32)(wb[k] >> (h * 32));
        uint32 ows = ~wh[0];                   // own b's word; bit==0 -> flip sign
        int rel = Tb - (c * CH_N + h * 32);
        uint32 vmask = (rel <= 0) ? 0u : ((rel >= 32) ? 0xFFFFFFFFu : ((1u << rel) - 1u));

        for (int tt = 0; tt < 32; ++tt) {
            int base = (h * 32 + tt) * M_N + s * 16;
            union { uint4 q4[2]; uint32 w[8]; h2 v2[8]; } W, Rm;
            W.q4[0] = *(const uint4*)&wbuf[base];
            W.q4[1] = *((const uint4*)&wbuf[base] + 1);
            Rm.q4[0] = *(const uint4*)&rbuf[base];
            Rm.q4[1] = *((const uint4*)&rbuf[base] + 1);

            float d[4];
            #pragma unroll
            for (int k = 0; k < 4; ++k) {
                float acc = 0.f;
                #pragma unroll
                for (int j = 0; j < 8; ++j) acc = fdot2(R2[k][j].v2, W.v2[j], acc);
                d[k] = acc;
            }
            // select-free butterfly: each stage's partner holds OUR b's partial
            float xa = dpp_add<0xB1>(d[0], d[1]);   // + lane s^1 (its d[1] = our b)
            float xb = dpp_add<0xB1>(d[2], d[3]);   // partial for b^2
            float uD = dpp_add<0x4E>(xa, xb);       // + lane s^2 (its xb = our b)
            uD = dpp_add<0x104>(uD, uD);            // + lane s+4 (row_shl:4)

            // softplus: -0.5*ln2 * log2(1 + 2^(2*log2e*y)), y = +-D by sign-xor
            uint32 sgn = bfe1(ows, tt) & 0x80000000u;
            float y = uas_f(fas_u(uD) ^ sgn);
            float contr = NHL2 * log2_n(1.f + exp2_n(LOG2E2 * y));
            sum += uas_f(fas_u(contr) & bfe1(vmask, tt));

            // update: R2 *= (1 + (r-1)&mask)  (bfe mask + AND + packed fma)
            #pragma unroll
            for (int k = 0; k < 4; ++k) {
                uint32 msk = bfe1(wh[k], tt);
                #pragma unroll
                for (int j = 0; j < 8; ++j) {
                    HU sel; sel.u = Rm.w[j] & msk;
                    R2[k][j].v2 += sel.v2 * R2[k][j].v2;
                }
            }
        }
    }
    if (s < 4) atomicAdd(&out[b0 + s], sum);
}

extern "C" void kernel_launch(void* const* d_in, const int* in_sizes, int n_in,
                              void* d_out, int out_size, void* d_ws, size_t ws_size,
                              hipStream_t stream) {
    const int*   inputs  = (const int*)d_in[0];     // (B, L) int32
    const float* epsilon = (const float*)d_in[1];   // (D, M, L) f32
    float* out = (float*)d_out;                     // (B,) f32

    char* ws = (char*)d_ws;
    _Float16* w16 = (_Float16*)(ws + OFF_W16);
    _Float16* r16 = (_Float16*)(ws + OFF_R16);
    u64*   bits   = (u64*)  (ws + OFF_BITS);
    unsigned short* lrT = (unsigned short*)(ws + OFF_LR);
    _Float16* Rq  = (_Float16*)(ws + OFF_RQ);
    int*   T      = (int*)  (ws + OFF_T);

    k_prep<<<PACK_BLK + EPS_BLK + ZERO_BLK, 256, 0, stream>>>(
        inputs, epsilon, bits, w16, r16, lrT, out);
    k_slog2<<<1024 + 32, 256, 0, stream>>>(bits, lrT, Rq, T);
    k_main<<<(B_N / 128) * C_N, 256, 0, stream>>>(bits, w16, r16, Rq, T, out);
}